// Round 7
// baseline (224.717 us; speedup 1.0000x reference)
//
#include <hip/hip_runtime.h>
#include <cstdint>

#define B_SZ   4
#define E_DIM  16
#define C_INST 24
#define HW_N   262144          // 512*512
#define NG     (HW_N / 4)      // 65536 float4 pixel-groups per (b, e)

#define DELTA_VAR  0.75f
#define DELTA_DIST 2.0f
#define ALPHA_W 1.0f
#define BETA_W  1.0f
#define GAMMA_W 0.001f

#define P1_BX    512                     // blocks per batch -> 8 blocks/CU
#define P1_WPX   (HW_N / (P1_BX * 4))    // 128 px per wave
#define P1_STEPS (P1_WPX / 16)           // 8 independent k-steps per wave
#define P2_BX   256                      // R15-proven pass2 geometry
#define P2_TOTAL (P2_BX * B_SZ)          // 1024

typedef __attribute__((ext_vector_type(8)))  short bf16x8;   // 8 bf16 = 4 VGPR
typedef __attribute__((ext_vector_type(16))) float f32x16;   // MFMA 32x32 acc

__device__ __forceinline__ uint32_t bf16rne(float f) {       // fp32 -> bf16 RNE
    const uint32_t u = __float_as_uint(f);
    return (u + 0x7FFFu + ((u >> 16) & 1u)) >> 16;
}

// ---------------------------------------------------------------------------
// Pass 1 (R17): wave-independent MFMA one-hot segment-sum.
// R16 post-mortem: correct (absmax 0.0 validated ALL layouts) but 58.8us —
// occupancy 27% (grid-limited, 4 blocks/CU) and 8 barrier+vmcnt(0) drains
// per block around the cross-wave LDS staging. Fix: delete the coupling.
// Per 16-px k-step, lane c=l&31 loads its own B-fragment from GLOBAL
// (plane c, 8 px = 2 float4; lanes c/c+32 cover one 64B line -> no
// overfetch); labels broadcast-loaded by all lanes (same 64B line);
// one-hot A in regs; 1 mfma. NO barriers, NO x-LDS in the hot loop.
// 2048 blocks -> 8 blocks/CU; TLP + depth-1 prefetch covers HBM latency.
// A: row(class)=lane&31, k=8*(lane>>5)+j  [R16-validated]
// B: col(plane)=lane&31 (0..15 dims, 16 ones->counts, 17..31 zero), same k
// C/D: row=(r&3)+8*(r>>2)+4*(lane>>5), col=lane&31  [R16-validated]
// Lanes 17..23 still compute REAL one-hot rows (classes 17..23); their
// B-col is zero — roles are independent.
// ---------------------------------------------------------------------------
__global__ __launch_bounds__(256) void pass1_kernel(
    const float* __restrict__ input, const int* __restrict__ target,
    float* __restrict__ sums, float* __restrict__ counts)
{
    __shared__ float racc[4][C_INST][18];          // epilogue only (6.9 KB)
    const int tid  = threadIdx.x;
    const int l    = tid & 63;
    const int wv   = tid >> 6;
    const int b    = blockIdx.y;
    const int c    = l & 31;                       // A-row / B-col for this lane
    const int half = l >> 5;
    const bool isx = (c < E_DIM);

    const int wpx = (blockIdx.x * 4 + wv) * P1_WPX;
    const int* __restrict__ tgt = target + (size_t)b * HW_N;
    const float4* __restrict__ src4 =
        (const float4*)(input + (size_t)b * E_DIM * HW_N);

    f32x16 acc;
    #pragma unroll
    for (int r = 0; r < 16; ++r) acc[r] = 0.f;

    int4 la0, lb0, la1, lb1;
    float4 xa0 = {}, xb0 = {}, xa1 = {}, xb1 = {};

#define P1_LOAD(t, la, lb, xa, xb) do {                          \
        const int k0 = wpx + (t) * 16 + half * 8;                \
        la = *(const int4*)&tgt[k0];                             \
        lb = *(const int4*)&tgt[k0 + 4];                         \
        if (isx) {                                               \
            xa = src4[(size_t)c * NG + (k0 >> 2)];               \
            xb = src4[(size_t)c * NG + (k0 >> 2) + 1];           \
        }                                                        \
    } while (0)

#define P1_STEP(la, lb, xa, xb) do {                                              \
        union { uint32_t u[4]; bf16x8 v; } af, bf;                                \
        af.u[0] = ((la.x == c) ? 0x3F80u : 0u) | ((la.y == c) ? 0x3F800000u : 0u);\
        af.u[1] = ((la.z == c) ? 0x3F80u : 0u) | ((la.w == c) ? 0x3F800000u : 0u);\
        af.u[2] = ((lb.x == c) ? 0x3F80u : 0u) | ((lb.y == c) ? 0x3F800000u : 0u);\
        af.u[3] = ((lb.z == c) ? 0x3F80u : 0u) | ((lb.w == c) ? 0x3F800000u : 0u);\
        if (isx) {                                                                \
            bf.u[0] = bf16rne(xa.x) | (bf16rne(xa.y) << 16);                      \
            bf.u[1] = bf16rne(xa.z) | (bf16rne(xa.w) << 16);                      \
            bf.u[2] = bf16rne(xb.x) | (bf16rne(xb.y) << 16);                      \
            bf.u[3] = bf16rne(xb.z) | (bf16rne(xb.w) << 16);                      \
        } else if (c == E_DIM) {                                                  \
            bf.u[0] = bf.u[1] = bf.u[2] = bf.u[3] = 0x3F803F80u;                  \
        } else {                                                                  \
            bf.u[0] = bf.u[1] = bf.u[2] = bf.u[3] = 0u;                           \
        }                                                                         \
        acc = __builtin_amdgcn_mfma_f32_32x32x16_bf16(af.v, bf.v, acc, 0, 0, 0);  \
    } while (0)

    P1_LOAD(0, la0, lb0, xa0, xb0);
    #pragma unroll
    for (int t = 0; t < P1_STEPS; t += 2) {
        P1_LOAD(t + 1, la1, lb1, xa1, xb1);      // issue-early: next step's HBM
        P1_STEP(la0, lb0, xa0, xb0);
        if (t + 2 < P1_STEPS) P1_LOAD(t + 2, la0, lb0, xa0, xb0);
        P1_STEP(la1, lb1, xa1, xb1);
    }
#undef P1_LOAD
#undef P1_STEP

    // dump valid C/D fragments: each (row<24, col<17) held by exactly 1 lane
    #pragma unroll
    for (int r = 0; r < 16; ++r) {
        const int row = (r & 3) + 8 * (r >> 2) + 4 * half;
        if (row < C_INST && c < 17) racc[wv][row][c] = acc[r];
    }
    __syncthreads();
    for (int i = tid; i < C_INST * 17; i += 256) {
        const int cc = i / 17, e = i % 17;
        const float s = racc[0][cc][e] + racc[1][cc][e]
                      + racc[2][cc][e] + racc[3][cc][e];
        if (e < E_DIM)
            unsafeAtomicAdd(&sums[((size_t)b * E_DIM + e) * C_INST + cc], s);
        else
            unsafeAtomicAdd(&counts[b * C_INST + cc], s);
    }
}

// ---------------------------------------------------------------------------
// Pass 2 (R15-proven, unchanged): float4/thread, mu as float4 rows (16
// ds_read_b128/thread), distinct-slot partials.
// ---------------------------------------------------------------------------
__global__ __launch_bounds__(256) void pass2_kernel(
    const float* __restrict__ input, const int* __restrict__ target,
    const float* __restrict__ sums, const float* __restrict__ counts,
    float* __restrict__ partials)
{
    __shared__ float4 mu4[C_INST][5];    // [c][e4], e4<4 used; row 80 B
    __shared__ float w_l[C_INST];
    __shared__ float redw[4];
    const int tid  = threadIdx.x;
    const int lane = tid & 63;
    const int wv   = tid >> 6;
    const int b    = blockIdx.y;

    if (tid < C_INST) {
        const float cv = counts[b * C_INST + tid];
        w_l[tid] = (cv > 0.f) ? 1.f / cv : 0.f;
    }
    __syncthreads();
    for (int i = tid; i < E_DIM * C_INST; i += 256) {
        const int e = i / C_INST, c = i % C_INST;
        ((float*)&mu4[c][0])[e] =
            sums[((size_t)b * E_DIM + e) * C_INST + c] * w_l[c];
    }
    __syncthreads();

    const int g = blockIdx.x * 256 + tid;    // 256 blocks/batch, float4 groups
    const int4 lab4 = ((const int4*)(target + (size_t)b * HW_N))[g];
    const float4* __restrict__ src4 =
        (const float4*)(input + (size_t)b * E_DIM * HW_N);

    float4 xv[E_DIM];
    #pragma unroll
    for (int e = 0; e < E_DIM; ++e)
        xv[e] = src4[(size_t)e * NG + g];

    float d2[4] = {0.f, 0.f, 0.f, 0.f};
    #pragma unroll
    for (int e4 = 0; e4 < 4; ++e4) {
        const float4 mx = mu4[lab4.x][e4];
        const float4 my = mu4[lab4.y][e4];
        const float4 mz = mu4[lab4.z][e4];
        const float4 mw = mu4[lab4.w][e4];
        float df;
        df = xv[4*e4+0].x - mx.x; d2[0] = fmaf(df, df, d2[0]);
        df = xv[4*e4+1].x - mx.y; d2[0] = fmaf(df, df, d2[0]);
        df = xv[4*e4+2].x - mx.z; d2[0] = fmaf(df, df, d2[0]);
        df = xv[4*e4+3].x - mx.w; d2[0] = fmaf(df, df, d2[0]);
        df = xv[4*e4+0].y - my.x; d2[1] = fmaf(df, df, d2[1]);
        df = xv[4*e4+1].y - my.y; d2[1] = fmaf(df, df, d2[1]);
        df = xv[4*e4+2].y - my.z; d2[1] = fmaf(df, df, d2[1]);
        df = xv[4*e4+3].y - my.w; d2[1] = fmaf(df, df, d2[1]);
        df = xv[4*e4+0].z - mz.x; d2[2] = fmaf(df, df, d2[2]);
        df = xv[4*e4+1].z - mz.y; d2[2] = fmaf(df, df, d2[2]);
        df = xv[4*e4+2].z - mz.z; d2[2] = fmaf(df, df, d2[2]);
        df = xv[4*e4+3].z - mz.w; d2[2] = fmaf(df, df, d2[2]);
        df = xv[4*e4+0].w - mw.x; d2[3] = fmaf(df, df, d2[3]);
        df = xv[4*e4+1].w - mw.y; d2[3] = fmaf(df, df, d2[3]);
        df = xv[4*e4+2].w - mw.z; d2[3] = fmaf(df, df, d2[3]);
        df = xv[4*e4+3].w - mw.w; d2[3] = fmaf(df, df, d2[3]);
    }

    float vloc = 0.f;
    {
        const int lp[4] = {lab4.x, lab4.y, lab4.z, lab4.w};
        #pragma unroll
        for (int p = 0; p < 4; ++p) {
            const float h = fmaxf(sqrtf(d2[p]) - DELTA_VAR, 0.f);
            vloc = fmaf(h * h, w_l[lp[p]], vloc);
        }
    }
    #pragma unroll
    for (int m = 1; m < 64; m <<= 1) vloc += __shfl_xor(vloc, m, 64);
    if (lane == 0) redw[wv] = vloc;
    __syncthreads();
    if (tid == 0)
        partials[b * P2_BX + blockIdx.x] = redw[0] + redw[1] + redw[2] + redw[3];
}

// ---------------------------------------------------------------------------
// Final (proven): sum 1024 partials + pairwise distance + regularizer.
// ---------------------------------------------------------------------------
__global__ __launch_bounds__(256) void final_kernel(
    const float* __restrict__ sums, const float* __restrict__ counts,
    const float* __restrict__ partials, float* __restrict__ out)
{
    __shared__ float mu[B_SZ][C_INST][E_DIM];
    __shared__ float red[256];
    const int tid = threadIdx.x;

    for (int i = tid; i < B_SZ * C_INST * E_DIM; i += 256) {
        const int b = i / (C_INST * E_DIM);
        const int r = i % (C_INST * E_DIM);
        const int e = r / C_INST, c = r % C_INST;
        const float cv = counts[b * C_INST + c];
        mu[b][c][e] = (cv > 0.f)
            ? sums[((size_t)b * E_DIM + e) * C_INST + c] / cv : 0.f;
    }
    __syncthreads();

    float acc = 0.f;
    // variance partials (1024 slots, 4 per thread)
    #pragma unroll
    for (int i = 0; i < P2_TOTAL / 256; ++i)
        acc += partials[i * 256 + tid] * (ALPHA_W / (B_SZ * C_INST));
    // regularizer
    for (int i = tid; i < B_SZ * C_INST; i += 256) {
        const int b = i / C_INST, c = i % C_INST;
        float n2 = 0.f;
        #pragma unroll
        for (int e = 0; e < E_DIM; ++e) n2 += mu[b][c][e] * mu[b][c][e];
        acc += GAMMA_W * sqrtf(n2) * (1.0f / (B_SZ * C_INST));
    }
    // pairwise repulsion
    for (int i = tid; i < B_SZ * C_INST * C_INST; i += 256) {
        const int b  = i / (C_INST * C_INST);
        const int r  = i % (C_INST * C_INST);
        const int c1 = r / C_INST, c2 = r % C_INST;
        if (c1 != c2) {
            float d2 = 0.f;
            #pragma unroll
            for (int e = 0; e < E_DIM; ++e) {
                const float d = mu[b][c1][e] - mu[b][c2][e];
                d2 += d * d;
            }
            const float h = fmaxf(2.0f * DELTA_DIST - sqrtf(d2), 0.f);
            acc += BETA_W * h * h * (1.0f / (B_SZ * C_INST * (C_INST - 1)));
        }
    }

    red[tid] = acc;
    __syncthreads();
    for (int s = 128; s > 0; s >>= 1) {
        if (tid < s) red[tid] += red[tid + s];
        __syncthreads();
    }
    if (tid == 0) out[0] = red[0];
}

extern "C" void kernel_launch(void* const* d_in, const int* in_sizes, int n_in,
                              void* d_out, int out_size, void* d_ws, size_t ws_size,
                              hipStream_t stream)
{
    const float* input  = (const float*)d_in[0];
    const int*   target = (const int*)d_in[1];

    float* sums     = (float*)d_ws;                         // B*E*C ([b][e][c])
    float* counts   = sums + B_SZ * E_DIM * C_INST;         // B*C
    float* partials = counts + B_SZ * C_INST;               // 1024 (distinct slots)
    const size_t ws_zero_bytes =
        (size_t)(B_SZ * E_DIM * C_INST + B_SZ * C_INST) * sizeof(float);
    hipMemsetAsync(d_ws, 0, ws_zero_bytes, stream);

    pass1_kernel<<<dim3(P1_BX, B_SZ), 256, 0, stream>>>(input, target, sums, counts);
    pass2_kernel<<<dim3(P2_BX, B_SZ), 256, 0, stream>>>(input, target, sums, counts, partials);
    final_kernel<<<1, 256, 0, stream>>>(sums, counts, partials, (float*)d_out);
}

// Round 8
// 120.008 us; speedup vs baseline: 1.8725x; 1.8725x over previous
//
#include <hip/hip_runtime.h>
#include <cstdint>

#define B_SZ   4
#define E_DIM  16
#define C_INST 24
#define HW_N   262144          // 512*512
#define NG     (HW_N / 4)      // 65536 float4 pixel-groups per (b, e)
#define NG2    (HW_N / 2)      // 131072 float2 pixel-pairs per (b, e)

#define DELTA_VAR  0.75f
#define DELTA_DIST 2.0f
#define ALPHA_W 1.0f
#define BETA_W  1.0f
#define GAMMA_W 0.001f

#define P1_NB   32                       // chunks per (plane, b) — R15-proven
#define P1_ITER (NG / (P1_NB * 256))     // 8
#define CNT_PL  8                        // planes 0..7 count slice it==eg
#define P2_BX   512                      // R18: float2/thread -> 8 blocks/CU
#define P2_TOTAL (P2_BX * B_SZ)          // 2048

// ---------------------------------------------------------------------------
// Pass 1 (R15-proven, FROZEN): conflict-free bucket layout + prefetch-2.
//  - buk[C][256]: bank = tid%32 for every access (init, RMW, any label);
//    lanes i,i+32 2-way alias = free (m136). R14 measured 4.2M conflict
//    cycles on the row-major layout; this killed them.
//  - depth-2 register prefetch covers HBM latency (~900cy > depth-1 work).
//  - MFMA arc closed: R16 (LDS-staged, 58.8us: grid-limited + 8 barrier
//    drains) and R17 (wave-independent, 132us: per-lane plane loads = 17
//    cache lines/instruction, transaction-bound) both lose to this.
// ---------------------------------------------------------------------------
__global__ __launch_bounds__(256) void pass1_kernel(
    const float* __restrict__ input, const int* __restrict__ target,
    float* __restrict__ sums, float* __restrict__ counts)
{
    __shared__ float buk[C_INST][256];   // 24.6 KB -> 6 blocks/CU
    __shared__ float crow[4][C_INST];
    const int tid   = threadIdx.x;
    const int lane  = tid & 63;
    const int wv    = tid >> 6;
    const int chunk = blockIdx.x;
    const int eg    = blockIdx.y;        // 0..15 = embedding dim
    const int b     = blockIdx.z;

    #pragma unroll
    for (int c = 0; c < C_INST; ++c) buk[c][tid] = 0.f;   // own column: no sync

    const int4* __restrict__ tgt4 = (const int4*)(target + (size_t)b * HW_N);
    const float4* __restrict__ src4 =
        (const float4*)(input + ((size_t)b * E_DIM + eg) * HW_N);
    const int gbase = chunk * 256 * P1_ITER + tid;

    int scnt[C_INST];
    #pragma unroll
    for (int c = 0; c < C_INST; ++c) scnt[c] = 0;

    int4   lab0 = tgt4[gbase];
    float4 x0   = src4[gbase];
    int4   lab1 = tgt4[gbase + 256];
    float4 x1   = src4[gbase + 256];
    #pragma unroll
    for (int it = 0; it < P1_ITER; ++it) {
        const int4   lc = lab0;
        const float4 xc = x0;
        lab0 = lab1; x0 = x1;
        if (it + 2 < P1_ITER) {          // depth-2 register prefetch
            lab1 = tgt4[gbase + (it + 2) * 256];
            x1   = src4[gbase + (it + 2) * 256];
        }
        buk[lc.x][tid] += xc.x;          // bank = tid%32 regardless of label
        buk[lc.y][tid] += xc.y;
        buk[lc.z][tid] += xc.z;
        buk[lc.w][tid] += xc.w;
        if (eg < CNT_PL && it == eg) {   // uniform branch: count this slice once
            #pragma unroll
            for (int c = 0; c < C_INST; ++c) {
                scnt[c] += (int)__popcll(__ballot(lc.x == c))
                         + (int)__popcll(__ballot(lc.y == c))
                         + (int)__popcll(__ballot(lc.z == c))
                         + (int)__popcll(__ballot(lc.w == c));
            }
        }
    }
    if (lane == 0) {
        #pragma unroll
        for (int c = 0; c < C_INST; ++c) crow[wv][c] = (float)scnt[c];
    }
    __syncthreads();

    // reduce 256 columns -> 24 class sums; 8 threads/class; per-class rotation
    // (k+c)&31 keeps each wave's 64 reads at 2-way bank alias (= free).
    if (tid < 8 * C_INST) {
        const int c  = tid >> 3;
        const int r0 = tid & 7;
        float s = 0.f;
        #pragma unroll
        for (int k = 0; k < 32; ++k)
            s += buk[c][r0 + 8 * ((k + c) & 31)];
        s += __shfl_xor(s, 1, 64);
        s += __shfl_xor(s, 2, 64);
        s += __shfl_xor(s, 4, 64);
        if (r0 == 0)
            unsafeAtomicAdd(&sums[((size_t)b * E_DIM + eg) * C_INST + c], s);
    }
    if (eg < CNT_PL && tid < C_INST) {
        const float s = crow[0][tid] + crow[1][tid] + crow[2][tid] + crow[3][tid];
        unsafeAtomicAdd(&counts[b * C_INST + tid], s);
    }
}

// ---------------------------------------------------------------------------
// Pass 2 (R18): single variable changed vs R15 — float2/thread with 512
// blocks/batch (2048 blocks = 8 blocks/CU = 32 waves/CU, was 16). R13
// measured a pass2-shaped kernel at 25% occupancy, all pipes idle ->
// latency-uncovered streaming gather; TLP is the fix. xv shrinks 64->32
// VGPR so nothing binds. mu4 float4 rows kept (R15 win): 8 ds_read_b128
// per thread. Distinct-slot partials (2048), plain stores.
// ---------------------------------------------------------------------------
__global__ __launch_bounds__(256) void pass2_kernel(
    const float* __restrict__ input, const int* __restrict__ target,
    const float* __restrict__ sums, const float* __restrict__ counts,
    float* __restrict__ partials)
{
    __shared__ float4 mu4[C_INST][5];    // [c][e4], e4<4 used; row 80 B
    __shared__ float w_l[C_INST];
    __shared__ float redw[4];
    const int tid  = threadIdx.x;
    const int lane = tid & 63;
    const int wv   = tid >> 6;
    const int b    = blockIdx.y;

    if (tid < C_INST) {
        const float cv = counts[b * C_INST + tid];
        w_l[tid] = (cv > 0.f) ? 1.f / cv : 0.f;
    }
    __syncthreads();
    for (int i = tid; i < E_DIM * C_INST; i += 256) {
        const int e = i / C_INST, c = i % C_INST;
        ((float*)&mu4[c][0])[e] =
            sums[((size_t)b * E_DIM + e) * C_INST + c] * w_l[c];
    }
    __syncthreads();

    const int g = blockIdx.x * 256 + tid;    // 512 blocks/batch, float2 pairs
    const int2 lab2 = ((const int2*)(target + (size_t)b * HW_N))[g];
    const float2* __restrict__ src2 =
        (const float2*)(input + (size_t)b * E_DIM * HW_N);

    float2 xv[E_DIM];
    #pragma unroll
    for (int e = 0; e < E_DIM; ++e)
        xv[e] = src2[(size_t)e * NG2 + g];

    float d2[2] = {0.f, 0.f};
    #pragma unroll
    for (int e4 = 0; e4 < 4; ++e4) {
        const float4 mx = mu4[lab2.x][e4];
        const float4 my = mu4[lab2.y][e4];
        float df;
        df = xv[4*e4+0].x - mx.x; d2[0] = fmaf(df, df, d2[0]);
        df = xv[4*e4+1].x - mx.y; d2[0] = fmaf(df, df, d2[0]);
        df = xv[4*e4+2].x - mx.z; d2[0] = fmaf(df, df, d2[0]);
        df = xv[4*e4+3].x - mx.w; d2[0] = fmaf(df, df, d2[0]);
        df = xv[4*e4+0].y - my.x; d2[1] = fmaf(df, df, d2[1]);
        df = xv[4*e4+1].y - my.y; d2[1] = fmaf(df, df, d2[1]);
        df = xv[4*e4+2].y - my.z; d2[1] = fmaf(df, df, d2[1]);
        df = xv[4*e4+3].y - my.w; d2[1] = fmaf(df, df, d2[1]);
    }

    float vloc = 0.f;
    {
        const int lp[2] = {lab2.x, lab2.y};
        #pragma unroll
        for (int p = 0; p < 2; ++p) {
            const float h = fmaxf(sqrtf(d2[p]) - DELTA_VAR, 0.f);
            vloc = fmaf(h * h, w_l[lp[p]], vloc);
        }
    }
    #pragma unroll
    for (int m = 1; m < 64; m <<= 1) vloc += __shfl_xor(vloc, m, 64);
    if (lane == 0) redw[wv] = vloc;
    __syncthreads();
    if (tid == 0)
        partials[b * P2_BX + blockIdx.x] = redw[0] + redw[1] + redw[2] + redw[3];
}

// ---------------------------------------------------------------------------
// Final (proven): sum 2048 partials + pairwise distance + regularizer.
// ---------------------------------------------------------------------------
__global__ __launch_bounds__(256) void final_kernel(
    const float* __restrict__ sums, const float* __restrict__ counts,
    const float* __restrict__ partials, float* __restrict__ out)
{
    __shared__ float mu[B_SZ][C_INST][E_DIM];
    __shared__ float red[256];
    const int tid = threadIdx.x;

    for (int i = tid; i < B_SZ * C_INST * E_DIM; i += 256) {
        const int b = i / (C_INST * E_DIM);
        const int r = i % (C_INST * E_DIM);
        const int e = r / C_INST, c = r % C_INST;
        const float cv = counts[b * C_INST + c];
        mu[b][c][e] = (cv > 0.f)
            ? sums[((size_t)b * E_DIM + e) * C_INST + c] / cv : 0.f;
    }
    __syncthreads();

    float acc = 0.f;
    // variance partials (2048 slots, 8 per thread)
    #pragma unroll
    for (int i = 0; i < P2_TOTAL / 256; ++i)
        acc += partials[i * 256 + tid] * (ALPHA_W / (B_SZ * C_INST));
    // regularizer
    for (int i = tid; i < B_SZ * C_INST; i += 256) {
        const int b = i / C_INST, c = i % C_INST;
        float n2 = 0.f;
        #pragma unroll
        for (int e = 0; e < E_DIM; ++e) n2 += mu[b][c][e] * mu[b][c][e];
        acc += GAMMA_W * sqrtf(n2) * (1.0f / (B_SZ * C_INST));
    }
    // pairwise repulsion
    for (int i = tid; i < B_SZ * C_INST * C_INST; i += 256) {
        const int b  = i / (C_INST * C_INST);
        const int r  = i % (C_INST * C_INST);
        const int c1 = r / C_INST, c2 = r % C_INST;
        if (c1 != c2) {
            float d2 = 0.f;
            #pragma unroll
            for (int e = 0; e < E_DIM; ++e) {
                const float d = mu[b][c1][e] - mu[b][c2][e];
                d2 += d * d;
            }
            const float h = fmaxf(2.0f * DELTA_DIST - sqrtf(d2), 0.f);
            acc += BETA_W * h * h * (1.0f / (B_SZ * C_INST * (C_INST - 1)));
        }
    }

    red[tid] = acc;
    __syncthreads();
    for (int s = 128; s > 0; s >>= 1) {
        if (tid < s) red[tid] += red[tid + s];
        __syncthreads();
    }
    if (tid == 0) out[0] = red[0];
}

extern "C" void kernel_launch(void* const* d_in, const int* in_sizes, int n_in,
                              void* d_out, int out_size, void* d_ws, size_t ws_size,
                              hipStream_t stream)
{
    const float* input  = (const float*)d_in[0];
    const int*   target = (const int*)d_in[1];

    float* sums     = (float*)d_ws;                         // B*E*C ([b][e][c])
    float* counts   = sums + B_SZ * E_DIM * C_INST;         // B*C
    float* partials = counts + B_SZ * C_INST;               // 2048 (distinct slots)
    const size_t ws_zero_bytes =
        (size_t)(B_SZ * E_DIM * C_INST + B_SZ * C_INST) * sizeof(float);
    hipMemsetAsync(d_ws, 0, ws_zero_bytes, stream);

    pass1_kernel<<<dim3(P1_NB, E_DIM, B_SZ), 256, 0, stream>>>(input, target, sums, counts);
    pass2_kernel<<<dim3(P2_BX, B_SZ), 256, 0, stream>>>(input, target, sums, counts, partials);
    final_kernel<<<1, 256, 0, stream>>>(sums, counts, partials, (float*)d_out);
}